// Round 1
// baseline (236.602 us; speedup 1.0000x reference)
//
#include <hip/hip_runtime.h>

#define Bn 4
#define Hn 512
#define Wn 512
#define HWn (Hn * Wn)

constexpr float kEps = 1e-5f;

// ws layout (floats):
// [0..3]  gmax bits per batch (uint, init 0; values >= 0 so uint-max == float-max)
// [4]     S1 = sum(r * w_blf)
// [5]     S2 = sum(w_blf)
// [16...] hdr_pow (B*HW floats)

__global__ void zero_ws(float* ws) {
  if (threadIdx.x < 16) ws[threadIdx.x] = 0.0f;
}

__global__ void prep_kernel(const float* __restrict__ hdr,
                            const float* __restrict__ gray,
                            const float* __restrict__ ff,
                            float* __restrict__ hdr_pow,
                            unsigned int* __restrict__ gmax_bits) {
  const int b = blockIdx.y;
  const float e = 1.0f - ff[b];
  const float* hb = hdr + b * HWn;
  const float* gb = gray + b * HWn;
  float* pb = hdr_pow + b * HWn;
  float lmax = 0.0f;
  for (int i = blockIdx.x * blockDim.x + threadIdx.x; i < HWn;
       i += blockDim.x * gridDim.x) {
    pb[i] = powf(hb[i], e);
    lmax = fmaxf(lmax, gb[i]);
  }
#pragma unroll
  for (int off = 32; off > 0; off >>= 1)
    lmax = fmaxf(lmax, __shfl_down(lmax, off));
  __shared__ float smax[4];
  const int lane = threadIdx.x & 63, wid = threadIdx.x >> 6;
  if (lane == 0) smax[wid] = lmax;
  __syncthreads();
  if (threadIdx.x == 0) {
    float m = smax[0];
    for (int i = 1; i < (int)(blockDim.x >> 6); ++i) m = fmaxf(m, smax[i]);
    atomicMax(&gmax_bits[b], __float_as_uint(m));
  }
}

__global__ __launch_bounds__(256) void main_kernel(
    const float* __restrict__ fake, const float* __restrict__ gamma,
    const float* __restrict__ rw, const float* __restrict__ ff,
    const float* __restrict__ hdr_pow,
    const unsigned int* __restrict__ gmax_bits, float* __restrict__ acc) {
  const int t = blockIdx.x * blockDim.x + threadIdx.x;  // one thread = 4 pixels
  const int pp = t << 2;
  const int b = pp / HWn;
  const int hw = pp - b * HWn;
  const int h = hw / Wn;
  const int w0 = hw - h * Wn;  // multiple of 4 -> float4-aligned rw loads

  float Sw[4] = {0, 0, 0, 0}, Sf[4] = {0, 0, 0, 0}, Sf2[4] = {0, 0, 0, 0};
  float Sg[4] = {0, 0, 0, 0}, Sg2[4] = {0, 0, 0, 0}, Sh[4] = {0, 0, 0, 0};

  const float* fbase = fake + b * HWn;
  const float* gbase = gamma + b * HWn;
  const float* pbase = hdr_pow + b * HWn;
  const float* rwbase = rw + (size_t)b * 25 * HWn + hw;

#pragma unroll
  for (int dyi = 0; dyi < 5; ++dyi) {
    const int row = h + dyi - 2;
    const bool rowok = (unsigned)row < (unsigned)Hn;
    const int rc = min(max(row, 0), Hn - 1);  // clamp: always-safe load, zero via mask
    const float* fr = fbase + rc * Wn;
    const float* gr = gbase + rc * Wn;
    const float* pr = pbase + rc * Wn;
    float xf[8], xg[8], xh[8];
#pragma unroll
    for (int i = 0; i < 8; ++i) {
      const int col = w0 - 2 + i;
      const bool ok = rowok && ((unsigned)col < (unsigned)Wn);
      const int cc = min(max(col, 0), Wn - 1);
      const float m = ok ? 1.0f : 0.0f;
      xf[i] = fr[cc] * m;
      xg[i] = gr[cc] * m;
      xh[i] = pr[cc] * m;
    }
#pragma unroll
    for (int dxi = 0; dxi < 5; ++dxi) {
      const int k = dyi * 5 + dxi;
      const float4 w4 = *(const float4*)(rwbase + (size_t)k * HWn);
      const float wk[4] = {w4.x, w4.y, w4.z, w4.w};
#pragma unroll
      for (int j = 0; j < 4; ++j) {
        const float wv = wk[j];
        const float f = xf[j + dxi], g = xg[j + dxi], hp = xh[j + dxi];
        Sw[j] += wv;
        Sf[j] = fmaf(wv, f, Sf[j]);
        Sf2[j] = fmaf(wv * f, f, Sf2[j]);
        Sg[j] = fmaf(wv, g, Sg[j]);
        Sg2[j] = fmaf(wv * g, g, Sg2[j]);
        Sh[j] = fmaf(wv, hp, Sh[j]);
      }
    }
  }

  const float ffb = ff[b];
  const float gmax = __uint_as_float(gmax_bits[b]);
  float s1 = 0.0f, s2 = 0.0f;
#pragma unroll
  for (int j = 0; j < 4; ++j) {
    const float invSw = 1.0f / Sw[j];
    const float muf = Sf[j] * invSw;
    const float varf = fmaxf(Sf2[j] * invSw - muf * muf, 0.0f);
    const float stdf = sqrtf(varf + kEps);
    const float mug = Sg[j] * invSw;
    const float varg = fmaxf(Sg2[j] * invSw - mug * mug, 0.0f);
    const float stdg = sqrtf(varg + kEps);
    const float hpmu = Sh[j] * invSw;
    const float stdobj = (1.0f / ffb) * stdg * (hpmu + kEps) * gmax;
    const float r = 1.0f - stdf / (stdf + stdobj);
    const float wblf = Sw[j] - 1.0f;
    s1 = fmaf(r, wblf, s1);
    s2 += wblf;
  }
#pragma unroll
  for (int off = 32; off > 0; off >>= 1) {
    s1 += __shfl_down(s1, off);
    s2 += __shfl_down(s2, off);
  }
  __shared__ float sh1[4], sh2[4];
  const int lane = threadIdx.x & 63, wid = threadIdx.x >> 6;
  if (lane == 0) {
    sh1[wid] = s1;
    sh2[wid] = s2;
  }
  __syncthreads();
  if (threadIdx.x == 0) {
    atomicAdd(&acc[0], sh1[0] + sh1[1] + sh1[2] + sh1[3]);
    atomicAdd(&acc[1], sh2[0] + sh2[1] + sh2[2] + sh2[3]);
  }
}

__global__ void final_kernel(const float* __restrict__ acc,
                             float* __restrict__ out) {
  if (threadIdx.x == 0) out[0] = acc[0] / acc[1];
}

extern "C" void kernel_launch(void* const* d_in, const int* in_sizes, int n_in,
                              void* d_out, int out_size, void* d_ws,
                              size_t ws_size, hipStream_t stream) {
  const float* fake = (const float*)d_in[0];
  const float* gamma = (const float*)d_in[1];
  const float* hdr = (const float*)d_in[2];
  const float* rw = (const float*)d_in[3];
  const float* ff = (const float*)d_in[4];
  const float* gray = (const float*)d_in[5];
  float* out = (float*)d_out;
  float* ws = (float*)d_ws;
  unsigned int* gmax_bits = (unsigned int*)ws;
  float* acc = ws + 4;
  float* hdr_pow = ws + 16;

  zero_ws<<<1, 64, 0, stream>>>(ws);
  prep_kernel<<<dim3(64, Bn), 256, 0, stream>>>(hdr, gray, ff, hdr_pow,
                                                gmax_bits);
  main_kernel<<<(Bn * HWn / 4) / 256, 256, 0, stream>>>(
      fake, gamma, rw, ff, hdr_pow, gmax_bits, acc);
  final_kernel<<<1, 64, 0, stream>>>(acc, out);
}